// Round 9
// baseline (236.705 us; speedup 1.0000x reference)
//
#include <hip/hip_runtime.h>

#define NP    128
#define NITER 100
#define RSC   72.13475204444817f    // log2(e)/EPS, EPS=0.02
#define IRSC  0.013862943611198906f // EPS*ln2 = 1/RSC

typedef __attribute__((ext_vector_type(8))) short bf16x8;
typedef __attribute__((ext_vector_type(4))) float f32x4;

__device__ __forceinline__ float wsum64(float x) {
  #pragma unroll
  for (int s = 1; s < 64; s <<= 1) x += __shfl_xor(x, s);
  return x;
}
__device__ __forceinline__ float bf2f(unsigned short h) {
  return __uint_as_float(((unsigned)h) << 16);
}
__device__ __forceinline__ unsigned short f2bf(float f) {   // RNE
  unsigned u = __float_as_uint(f);
  u += 0x7fffu + ((u >> 16) & 1u);
  return (unsigned short)(u >> 16);
}

// Linear-domain Sinkhorn, ONE WAVE PER PROBLEM.
//   K = 2^(-dist*RSC) held in registers in BOTH MFMA operand forms:
//     KA[rt][kt]: A-form, K[16rt+li][32kt+8lg+i]   (pass1: K·Q)
//     KB[ct][kt]: B-form, K[32kt+8lg+i][16ct+li]   (pass2: K^T·P)
//   Slack bin 128 folded into MFMA C-init (D = C + sum AB, C = q128/p128).
//   P/Q cross-lane redistribution via LDS; fences are __syncthreads() —
//   for a 1-wave block this is just waitcnt+retiring-barrier, but carries
//   full compiler-visible ordering (R8's inline-asm lgkmcnt fences NaN'd:
//   guide rule #18 hazard class).
__global__ __launch_bounds__(64, 1) void emd_sinkhorn(
    const float* __restrict__ j1g, const float* __restrict__ j2g,
    float* __restrict__ out)
{
  __shared__ __align__(16) float x1s[NP], y1s[NP], x2s[NP], y2s[NP];
  __shared__ __align__(16) float ahs[NP], bhs[NP];
  __shared__ __align__(16) float Slds[NP];
  __shared__ __align__(16) unsigned short Plds[NP];
  __shared__ __align__(16) unsigned short Qlds[NP];

  const int l  = threadIdx.x;        // lane 0..63
  const int lg = l >> 4;             // k-group 0..3
  const int li = l & 15;             // tile row/col 0..15
  const int b  = blockIdx.x;
  const float* J1 = j1g + (size_t)b * (NP * 3);
  const float* J2 = j2g + (size_t)b * (NP * 3);

  // ---- load particles (2 per lane) ----
  #pragma unroll
  for (int k = l; k < NP; k += 64) {
    x1s[k] = J1[3*k]; y1s[k] = J1[3*k+1]; ahs[k] = J1[3*k+2];
    x2s[k] = J2[3*k]; y2s[k] = J2[3*k+1]; bhs[k] = J2[3*k+2];
  }
  __syncthreads();

  // ---- energies (raw weights), slack masses, floored per-lane weights ----
  const float e1 = wsum64(ahs[l] + ahs[l + 64]);
  const float e2 = wsum64(bhs[l] + bhs[l + 64]);
  const float dE = fabsf(e2 - e1);
  const float aslk = fmaxf(fmaxf(e2 - e1, 0.0f), 1e-30f);
  const float bslk = fmaxf(fmaxf(e1 - e2, 0.0f), 1e-30f);
  const float2 araw = *(const float2*)&ahs[2*l];
  const float2 braw = *(const float2*)&bhs[2*l];
  const float ah0 = fmaxf(araw.x, 1e-30f), ah1 = fmaxf(araw.y, 1e-30f);
  const float bh0 = fmaxf(braw.x, 1e-30f), bh1 = fmaxf(braw.y, 1e-30f);

  // ---- build dual K fragments (once); coords read from LDS (broadcast) ----
  bf16x8 KA[8][4], KB[8][4];
  #pragma unroll
  for (int rt = 0; rt < 8; ++rt) {
    const float xr = x1s[16*rt + li], yr = y1s[16*rt + li];
    #pragma unroll
    for (int kt = 0; kt < 4; ++kt) {
      #pragma unroll
      for (int i2 = 0; i2 < 8; ++i2) {
        const int k = 32*kt + 8*lg + i2;
        const float dx = x2s[k] - xr + 1e-12f;
        const float dy = y2s[k] - yr + 1e-12f;
        KA[rt][kt][i2] = (short)f2bf(
            __builtin_amdgcn_exp2f(-__builtin_sqrtf(dx*dx + dy*dy) * RSC));
      }
    }
  }
  #pragma unroll
  for (int ct = 0; ct < 8; ++ct) {
    const float xc = x2s[16*ct + li], yc = y2s[16*ct + li];
    #pragma unroll
    for (int kt = 0; kt < 4; ++kt) {
      #pragma unroll
      for (int i2 = 0; i2 < 8; ++i2) {
        const int k = 32*kt + 8*lg + i2;
        const float dx = xc - x1s[k] + 1e-12f;
        const float dy = yc - y1s[k] + 1e-12f;
        KB[ct][kt][i2] = (short)f2bf(
            __builtin_amdgcn_exp2f(-__builtin_sqrtf(dx*dx + dy*dy) * RSC));
      }
    }
  }

  // ---- init: Q = 1 (g=0), q128 = 1, sumQ = 128 ----
  ((unsigned*)Qlds)[l] = 0x3F803F80u;
  float SQ = 128.0f, q128 = 1.0f;
  __syncthreads();

  for (int it = 0; it < NITER; ++it) {
    const float p128 = aslk * __builtin_amdgcn_rcpf(SQ + q128);

    // -------- pass1: s = K·Q + q128 (C-init) ; P = a * rcp(s) --------
    bf16x8 qf[4];
    #pragma unroll
    for (int kt = 0; kt < 4; ++kt)
      qf[kt] = *(const bf16x8*)((const char*)Qlds + 64*kt + 16*lg);
    f32x4 acc[8];
    #pragma unroll
    for (int rt = 0; rt < 8; ++rt) {
      acc[rt] = (f32x4){q128, q128, q128, q128};
      #pragma unroll
      for (int kt = 0; kt < 4; ++kt)
        acc[rt] = __builtin_amdgcn_mfma_f32_16x16x32_bf16(
            KA[rt][kt], qf[kt], acc[rt], 0, 0, 0);
    }
    if (li == 0) {
      #pragma unroll
      for (int rt = 0; rt < 8; ++rt)
        *(f32x4*)&Slds[16*rt + 4*lg] = acc[rt];   // rows 16rt+4lg+reg
    }
    __syncthreads();
    const float2 s2 = *(const float2*)&Slds[2*l]; // rows 2l, 2l+1
    const float P0 = ah0 * __builtin_amdgcn_rcpf(s2.x);
    const float P1 = ah1 * __builtin_amdgcn_rcpf(s2.y);
    const float SP = wsum64(P0 + P1);
    const float q128n = bslk * __builtin_amdgcn_rcpf(SP + p128);
    ((unsigned*)Plds)[l] =
        (unsigned)f2bf(P0) | ((unsigned)f2bf(P1) << 16);
    __syncthreads();

    // -------- pass2: s' = K^T·P + p128 (C-init) ; Q = b * rcp(s') --------
    bf16x8 pf[4];
    #pragma unroll
    for (int kt = 0; kt < 4; ++kt)
      pf[kt] = *(const bf16x8*)((const char*)Plds + 64*kt + 16*lg);
    f32x4 acc2[8];
    #pragma unroll
    for (int ct = 0; ct < 8; ++ct) {
      acc2[ct] = (f32x4){p128, p128, p128, p128};
      #pragma unroll
      for (int kt = 0; kt < 4; ++kt)
        acc2[ct] = __builtin_amdgcn_mfma_f32_16x16x32_bf16(
            pf[kt], KB[ct][kt], acc2[ct], 0, 0, 0);
    }
    if (lg == 0) {
      #pragma unroll
      for (int ct = 0; ct < 8; ++ct)
        Slds[16*ct + li] = acc2[ct][0];           // col 16ct+li (rows redundant)
    }
    __syncthreads();
    const float2 t2 = *(const float2*)&Slds[2*l]; // cols 2l, 2l+1
    const float Q0 = bh0 * __builtin_amdgcn_rcpf(t2.x);
    const float Q1 = bh1 * __builtin_amdgcn_rcpf(t2.y);
    SQ = wsum64(Q0 + Q1);
    ((unsigned*)Qlds)[l] =
        (unsigned)f2bf(Q0) | ((unsigned)f2bf(Q1) << 16);
    q128 = q128n;
    __syncthreads();
  }

  // ---- emd = sum_{n,m<128} d * P[n] Q[m] K[n][m] + dE ; d = -log2(K)*IRSC ----
  bf16x8 qf[4];
  #pragma unroll
  for (int kt = 0; kt < 4; ++kt)
    qf[kt] = *(const bf16x8*)((const char*)Qlds + 64*kt + 16*lg);
  float accE = 0.0f;
  #pragma unroll
  for (int rt = 0; rt < 8; ++rt) {
    const float Pn = bf2f(Plds[16*rt + li]);
    #pragma unroll
    for (int kt = 0; kt < 4; ++kt) {
      #pragma unroll
      for (int i2 = 0; i2 < 8; ++i2) {
        const float kk = bf2f((unsigned short)KA[rt][kt][i2]);
        const float qm = bf2f((unsigned short)qf[kt][i2]);
        const float d  = -__builtin_amdgcn_logf(kk) * IRSC;
        accE = fmaf(d, (Pn * kk) * qm, accE);
      }
    }
  }
  accE = wsum64(accE);
  if (l == 0) out[b] = accE + dE;
}

extern "C" void kernel_launch(void* const* d_in, const int* in_sizes, int n_in,
                              void* d_out, int out_size, void* d_ws, size_t ws_size,
                              hipStream_t stream) {
  const float* j1 = (const float*)d_in[0];
  const float* j2 = (const float*)d_in[1];
  float* outp = (float*)d_out;
  const int batch = in_sizes[0] / (NP * 3);
  hipLaunchKernelGGL(emd_sinkhorn, dim3(batch), dim3(64), 0, stream,
                     j1, j2, outp);
}

// Round 10
// 232.899 us; speedup vs baseline: 1.0163x; 1.0163x over previous
//
#include <hip/hip_runtime.h>

#define NP    128
#define NITER 100
#define RSC   72.13475204444817f    // log2(e)/EPS, EPS=0.02
#define IRSC  0.013862943611198906f // EPS*ln2 = 1/RSC

typedef __attribute__((ext_vector_type(8))) short bf16x8;
typedef __attribute__((ext_vector_type(4))) float f32x4;

__device__ __forceinline__ float wsum64(float x) {
  #pragma unroll
  for (int s = 1; s < 64; s <<= 1) x += __shfl_xor(x, s);
  return x;
}
__device__ __forceinline__ float bf2f(unsigned short h) {
  return __uint_as_float(((unsigned)h) << 16);
}
__device__ __forceinline__ unsigned short f2bf(float f) {   // RNE
  unsigned u = __float_as_uint(f);
  u += 0x7fffu + ((u >> 16) & 1u);
  return (unsigned short)(u >> 16);
}

// Linear-domain Sinkhorn, TWO WAVES PER PROBLEM (anti-spill split of R9):
//   wave w holds KA = K rows 64w..64w+63 (A-form, 64 VGPR) and
//                KB = K cols 64w..64w+63 (B-form, 64 VGPR).
//   pass1: wave w computes s-rows 64w.. via mfma(KA, Qrep), C-init q128.
//   pass2: wave w computes s'-cols 64w.. via mfma(Prep, KB), C-init p128.
//   Cross-wave: only the 128 sums via Slds/Tlds + 2 barriers/iter
//   (separate arrays -> R/W windows disjoint between barriers).
//   P/Q -> B-fragment redistribution: 16 ds_bpermute from packed pairs
//   (register-only, no LDS fence — avoids the R8 hazard class entirely).
__global__ __launch_bounds__(128, 2) void emd_sinkhorn(
    const float* __restrict__ j1g, const float* __restrict__ j2g,
    float* __restrict__ out)
{
  __shared__ __align__(16) float x1s[NP], y1s[NP], x2s[NP], y2s[NP];
  __shared__ __align__(16) float ahs[NP], bhs[NP];
  __shared__ __align__(16) float Slds[NP];   // pass1 row sums
  __shared__ __align__(16) float Tlds[NP];   // pass2 col sums
  __shared__ float red[2];

  const int t  = threadIdx.x;        // 0..127
  const int l  = t & 63;             // lane
  const int wv = t >> 6;             // wave 0..1: owns rows/cols 64wv..64wv+63
  const int lg = l >> 4;             // k-group 0..3
  const int li = l & 15;             // tile row/col 0..15
  const int b  = blockIdx.x;
  const float* J1 = j1g + (size_t)b * (NP * 3);
  const float* J2 = j2g + (size_t)b * (NP * 3);

  // ---- load particles (1 per thread) ----
  if (t < NP) {
    x1s[t] = J1[3*t]; y1s[t] = J1[3*t+1]; ahs[t] = J1[3*t+2];
    x2s[t] = J2[3*t]; y2s[t] = J2[3*t+1]; bhs[t] = J2[3*t+2];
  }
  __syncthreads();

  // ---- energies (raw weights; redundant per wave, deterministic) ----
  const float e1 = wsum64(ahs[l] + ahs[l + 64]);
  const float e2 = wsum64(bhs[l] + bhs[l + 64]);
  const float dE = fabsf(e2 - e1);
  const float aslk = fmaxf(fmaxf(e2 - e1, 0.0f), 1e-30f);
  const float bslk = fmaxf(fmaxf(e1 - e2, 0.0f), 1e-30f);
  const float2 araw = *(const float2*)&ahs[2*l];
  const float2 braw = *(const float2*)&bhs[2*l];
  const float ah0 = fmaxf(araw.x, 1e-30f), ah1 = fmaxf(araw.y, 1e-30f);
  const float bh0 = fmaxf(braw.x, 1e-30f), bh1 = fmaxf(braw.y, 1e-30f);

  // ---- build this wave's K fragments (once) ----
  bf16x8 KA[4][4], KB[4][4];
  #pragma unroll
  for (int rt = 0; rt < 4; ++rt) {
    const int n = 64*wv + 16*rt + li;
    const float xr = x1s[n], yr = y1s[n];
    #pragma unroll
    for (int kt = 0; kt < 4; ++kt) {
      #pragma unroll
      for (int i2 = 0; i2 < 8; ++i2) {
        const int k = 32*kt + 8*lg + i2;
        const float dx = x2s[k] - xr + 1e-12f;
        const float dy = y2s[k] - yr + 1e-12f;
        KA[rt][kt][i2] = (short)f2bf(
            __builtin_amdgcn_exp2f(-__builtin_sqrtf(dx*dx + dy*dy) * RSC));
      }
    }
  }
  #pragma unroll
  for (int ct = 0; ct < 4; ++ct) {
    const int m = 64*wv + 16*ct + li;
    const float xc = x2s[m], yc = y2s[m];
    #pragma unroll
    for (int kt = 0; kt < 4; ++kt) {
      #pragma unroll
      for (int i2 = 0; i2 < 8; ++i2) {
        const int k = 32*kt + 8*lg + i2;
        const float dx = xc - x1s[k] + 1e-12f;
        const float dy = yc - y1s[k] + 1e-12f;
        KB[ct][kt][i2] = (short)f2bf(
            __builtin_amdgcn_exp2f(-__builtin_sqrtf(dx*dx + dy*dy) * RSC));
      }
    }
  }

  // ---- init: Q = 1 (g=0); lane l holds cols (2l, 2l+1) packed ----
  unsigned Qpk = 0x3F803F80u;
  unsigned Ppk = 0;
  float SQ = 128.0f, q128 = 1.0f;

  for (int it = 0; it < NITER; ++it) {
    const float p128 = aslk * __builtin_amdgcn_rcpf(SQ + q128);

    // ---- gather Q into B-fragment form (register-only bpermute) ----
    bf16x8 qf[4];
    #pragma unroll
    for (int kt = 0; kt < 4; ++kt) {
      union { unsigned u[4]; bf16x8 v; } r;
      #pragma unroll
      for (int q = 0; q < 4; ++q)
        r.u[q] = (unsigned)__builtin_amdgcn_ds_bpermute(
            4*(16*kt + 4*lg + q), (int)Qpk);
      qf[kt] = r.v;
    }

    // -------- pass1: s-rows(own 64) = K·Q + q128 --------
    f32x4 acc[4];
    #pragma unroll
    for (int rt = 0; rt < 4; ++rt) {
      acc[rt] = (f32x4){q128, q128, q128, q128};
      #pragma unroll
      for (int kt = 0; kt < 4; ++kt)
        acc[rt] = __builtin_amdgcn_mfma_f32_16x16x32_bf16(
            KA[rt][kt], qf[kt], acc[rt], 0, 0, 0);
    }
    if (li == 0) {
      #pragma unroll
      for (int rt = 0; rt < 4; ++rt)
        *(f32x4*)&Slds[64*wv + 16*rt + 4*lg] = acc[rt];
    }
    __syncthreads();   // BAR1: Slds complete

    // ---- P for rows (2l, 2l+1), redundant in both waves ----
    const float2 s2 = *(const float2*)&Slds[2*l];
    const float P0 = ah0 * __builtin_amdgcn_rcpf(s2.x);
    const float P1 = ah1 * __builtin_amdgcn_rcpf(s2.y);
    const float SP = wsum64(P0 + P1);
    const float q128n = bslk * __builtin_amdgcn_rcpf(SP + p128);
    Ppk = (unsigned)f2bf(P0) | ((unsigned)f2bf(P1) << 16);

    // ---- gather P into B-fragment form ----
    bf16x8 pf[4];
    #pragma unroll
    for (int kt = 0; kt < 4; ++kt) {
      union { unsigned u[4]; bf16x8 v; } r;
      #pragma unroll
      for (int q = 0; q < 4; ++q)
        r.u[q] = (unsigned)__builtin_amdgcn_ds_bpermute(
            4*(16*kt + 4*lg + q), (int)Ppk);
      pf[kt] = r.v;
    }

    // -------- pass2: s'-cols(own 64) = K^T·P + p128 --------
    f32x4 acc2[4];
    #pragma unroll
    for (int ct = 0; ct < 4; ++ct) {
      acc2[ct] = (f32x4){p128, p128, p128, p128};
      #pragma unroll
      for (int kt = 0; kt < 4; ++kt)
        acc2[ct] = __builtin_amdgcn_mfma_f32_16x16x32_bf16(
            pf[kt], KB[ct][kt], acc2[ct], 0, 0, 0);
    }
    if (lg == 0) {
      #pragma unroll
      for (int ct = 0; ct < 4; ++ct)
        Tlds[64*wv + 16*ct + li] = acc2[ct][0];   // rows of D identical
    }
    __syncthreads();   // BAR2: Tlds complete

    // ---- Q for cols (2l, 2l+1), redundant in both waves ----
    const float2 t2 = *(const float2*)&Tlds[2*l];
    const float Q0 = bh0 * __builtin_amdgcn_rcpf(t2.x);
    const float Q1 = bh1 * __builtin_amdgcn_rcpf(t2.y);
    SQ = wsum64(Q0 + Q1);
    Qpk = (unsigned)f2bf(Q0) | ((unsigned)f2bf(Q1) << 16);
    q128 = q128n;
  }

  // ---- emd = sum_{n,m<128} d * P[n] Q[m] K[n][m] + dE ; d=-log2(K)*IRSC ----
  bf16x8 qf[4];
  #pragma unroll
  for (int kt = 0; kt < 4; ++kt) {
    union { unsigned u[4]; bf16x8 v; } r;
    #pragma unroll
    for (int q = 0; q < 4; ++q)
      r.u[q] = (unsigned)__builtin_amdgcn_ds_bpermute(
          4*(16*kt + 4*lg + q), (int)Qpk);
    qf[kt] = r.v;
  }
  float accE = 0.0f;
  #pragma unroll
  for (int rt = 0; rt < 4; ++rt) {
    const int n = 64*wv + 16*rt + li;
    const unsigned pr = (unsigned)__builtin_amdgcn_ds_bpermute(
        4*(n >> 1), (int)Ppk);
    const float Pn = bf2f((unsigned short)((li & 1) ? (pr >> 16) : pr));
    #pragma unroll
    for (int kt = 0; kt < 4; ++kt) {
      #pragma unroll
      for (int i2 = 0; i2 < 8; ++i2) {
        const float kk = bf2f((unsigned short)KA[rt][kt][i2]);
        const float qm = bf2f((unsigned short)qf[kt][i2]);
        const float d  = -__builtin_amdgcn_logf(kk) * IRSC;
        accE = fmaf(d, (Pn * kk) * qm, accE);
      }
    }
  }
  accE = wsum64(accE);
  if (l == 0) red[wv] = accE;
  __syncthreads();
  if (t == 0) out[b] = (red[0] + red[1]) + dE;
}

extern "C" void kernel_launch(void* const* d_in, const int* in_sizes, int n_in,
                              void* d_out, int out_size, void* d_ws, size_t ws_size,
                              hipStream_t stream) {
  const float* j1 = (const float*)d_in[0];
  const float* j2 = (const float*)d_in[1];
  float* outp = (float*)d_out;
  const int batch = in_sizes[0] / (NP * 3);
  hipLaunchKernelGGL(emd_sinkhorn, dim3(batch), dim3(128), 0, stream,
                     j1, j2, outp);
}

// Round 11
// 201.617 us; speedup vs baseline: 1.1740x; 1.1552x over previous
//
#include <hip/hip_runtime.h>

#define NP    128
#define NITER 100
#define RSC   72.13475204444817f    // log2(e)/EPS, EPS=0.02
#define IRSC  0.013862943611198906f // EPS*ln2 = 1/RSC

typedef __attribute__((ext_vector_type(8))) short bf16x8;
typedef __attribute__((ext_vector_type(4))) float f32x4;

__device__ __forceinline__ float wsum64(float x) {
  #pragma unroll
  for (int s = 1; s < 64; s <<= 1) x += __shfl_xor(x, s);
  return x;
}
__device__ __forceinline__ float bf2f(unsigned short h) {
  return __uint_as_float(((unsigned)h) << 16);
}
__device__ __forceinline__ unsigned short f2bf(float f) {   // RNE
  unsigned u = __float_as_uint(f);
  u += 0x7fffu + ((u >> 16) & 1u);
  return (unsigned short)(u >> 16);
}

// Linear-domain Sinkhorn, FOUR WAVES PER PROBLEM.
//   wave w holds KA = K rows 32w..32w+31 (A-form, 32 VGPR) and
//                KB = K cols 32w..32w+31 (B-form, 32 VGPR).
//   Register demand ~120 under a 256-reg budget (launch_bounds(256,2)) —
//   inside the allocation zone proven clean in R6/R7; R9/R10's >200-demand
//   configs spilled (93-147 MB scratch writes).
//   pass1: s-rows(own 32) = mfma(KA, Qrep) with C-init q128 -> Slds.
//   pass2: s'-cols(own 32) = mfma(Prep, KB) with C-init p128 -> Tlds.
//   P/Q/sums recomputed REDUNDANTLY in all waves from Slds/Tlds
//   (bit-identical => benign same-value races); 2 barriers/iter.
__global__ __launch_bounds__(256, 2) void emd_sinkhorn(
    const float* __restrict__ j1g, const float* __restrict__ j2g,
    float* __restrict__ out)
{
  __shared__ __align__(16) float x1s[NP], y1s[NP], x2s[NP], y2s[NP];
  __shared__ __align__(16) float ahs[NP], bhs[NP];
  __shared__ __align__(16) float Slds[NP];            // pass1 row sums
  __shared__ __align__(16) float Tlds[NP];            // pass2 col sums
  __shared__ __align__(16) unsigned short Plds[NP];   // bf16 P
  __shared__ __align__(16) unsigned short Qlds[NP];   // bf16 Q
  __shared__ float red[4];

  const int t  = threadIdx.x;        // 0..255
  const int l  = t & 63;             // lane
  const int wv = t >> 6;             // wave 0..3: owns rows/cols 32wv..32wv+31
  const int lg = l >> 4;             // k-group 0..3
  const int li = l & 15;             // tile row/col 0..15
  const int b  = blockIdx.x;
  const float* J1 = j1g + (size_t)b * (NP * 3);
  const float* J2 = j2g + (size_t)b * (NP * 3);

  // ---- load particles (threads 0..127) ----
  if (t < NP) {
    x1s[t] = J1[3*t]; y1s[t] = J1[3*t+1]; ahs[t] = J1[3*t+2];
    x2s[t] = J2[3*t]; y2s[t] = J2[3*t+1]; bhs[t] = J2[3*t+2];
  }
  __syncthreads();

  // ---- energies (raw weights; redundant per wave, deterministic) ----
  const float e1 = wsum64(ahs[l] + ahs[l + 64]);
  const float e2 = wsum64(bhs[l] + bhs[l + 64]);
  const float dE = fabsf(e2 - e1);
  const float aslk = fmaxf(fmaxf(e2 - e1, 0.0f), 1e-30f);
  const float bslk = fmaxf(fmaxf(e1 - e2, 0.0f), 1e-30f);
  const float2 araw = *(const float2*)&ahs[2*l];
  const float2 braw = *(const float2*)&bhs[2*l];
  const float ah0 = fmaxf(araw.x, 1e-30f), ah1 = fmaxf(araw.y, 1e-30f);
  const float bh0 = fmaxf(braw.x, 1e-30f), bh1 = fmaxf(braw.y, 1e-30f);

  // ---- build this wave's K fragments (once) ----
  bf16x8 KA[2][4], KB[2][4];
  #pragma unroll
  for (int rt = 0; rt < 2; ++rt) {
    const int n = 32*wv + 16*rt + li;
    const float xr = x1s[n], yr = y1s[n];
    #pragma unroll
    for (int kt = 0; kt < 4; ++kt) {
      #pragma unroll
      for (int i2 = 0; i2 < 8; ++i2) {
        const int k = 32*kt + 8*lg + i2;
        const float dx = x2s[k] - xr + 1e-12f;
        const float dy = y2s[k] - yr + 1e-12f;
        KA[rt][kt][i2] = (short)f2bf(
            __builtin_amdgcn_exp2f(-__builtin_sqrtf(dx*dx + dy*dy) * RSC));
      }
    }
  }
  #pragma unroll
  for (int ct = 0; ct < 2; ++ct) {
    const int m = 32*wv + 16*ct + li;
    const float xc = x2s[m], yc = y2s[m];
    #pragma unroll
    for (int kt = 0; kt < 4; ++kt) {
      #pragma unroll
      for (int i2 = 0; i2 < 8; ++i2) {
        const int k = 32*kt + 8*lg + i2;
        const float dx = xc - x1s[k] + 1e-12f;
        const float dy = yc - y1s[k] + 1e-12f;
        KB[ct][kt][i2] = (short)f2bf(
            __builtin_amdgcn_exp2f(-__builtin_sqrtf(dx*dx + dy*dy) * RSC));
      }
    }
  }

  // ---- init: Q = 1 (g=0); lane l holds (2l, 2l+1) packed ----
  ((unsigned*)Qlds)[l] = 0x3F803F80u;   // every wave writes same values
  float SQ = 128.0f, q128 = 1.0f;
  __syncthreads();

  for (int it = 0; it < NITER; ++it) {
    const float p128 = aslk * __builtin_amdgcn_rcpf(SQ + q128);

    // -------- pass1: s-rows(own 32) = K·Q + q128 --------
    bf16x8 qf[4];
    #pragma unroll
    for (int kt = 0; kt < 4; ++kt)
      qf[kt] = *(const bf16x8*)((const char*)Qlds + 64*kt + 16*lg);
    f32x4 acc[2];
    #pragma unroll
    for (int rt = 0; rt < 2; ++rt) {
      acc[rt] = (f32x4){q128, q128, q128, q128};
      #pragma unroll
      for (int kt = 0; kt < 4; ++kt)
        acc[rt] = __builtin_amdgcn_mfma_f32_16x16x32_bf16(
            KA[rt][kt], qf[kt], acc[rt], 0, 0, 0);
    }
    if (li == 0) {
      #pragma unroll
      for (int rt = 0; rt < 2; ++rt)
        *(f32x4*)&Slds[32*wv + 16*rt + 4*lg] = acc[rt];
    }
    __syncthreads();   // BAR1: Slds complete

    // ---- P for rows (2l, 2l+1), redundant in every wave ----
    const float2 s2 = *(const float2*)&Slds[2*l];
    const float P0 = ah0 * __builtin_amdgcn_rcpf(s2.x);
    const float P1 = ah1 * __builtin_amdgcn_rcpf(s2.y);
    const float SP = wsum64(P0 + P1);
    const float q128n = bslk * __builtin_amdgcn_rcpf(SP + p128);
    ((unsigned*)Plds)[l] = (unsigned)f2bf(P0) | ((unsigned)f2bf(P1) << 16);

    // -------- pass2: s'-cols(own 32) = K^T·P + p128 --------
    // pf read: in-wave dependency on this wave's own Plds writes (compiler
    // orders via lgkmcnt); concurrent identical writes from other waves are
    // benign same-value races.
    bf16x8 pf[4];
    #pragma unroll
    for (int kt = 0; kt < 4; ++kt)
      pf[kt] = *(const bf16x8*)((const char*)Plds + 64*kt + 16*lg);
    f32x4 acc2[2];
    #pragma unroll
    for (int ct = 0; ct < 2; ++ct) {
      acc2[ct] = (f32x4){p128, p128, p128, p128};
      #pragma unroll
      for (int kt = 0; kt < 4; ++kt)
        acc2[ct] = __builtin_amdgcn_mfma_f32_16x16x32_bf16(
            pf[kt], KB[ct][kt], acc2[ct], 0, 0, 0);
    }
    if (lg == 0) {
      #pragma unroll
      for (int ct = 0; ct < 2; ++ct)
        Tlds[32*wv + 16*ct + li] = acc2[ct][0];   // D rows identical
    }
    __syncthreads();   // BAR2: Tlds complete

    // ---- Q for cols (2l, 2l+1), redundant in every wave ----
    const float2 t2 = *(const float2*)&Tlds[2*l];
    const float Q0 = bh0 * __builtin_amdgcn_rcpf(t2.x);
    const float Q1 = bh1 * __builtin_amdgcn_rcpf(t2.y);
    SQ = wsum64(Q0 + Q1);
    ((unsigned*)Qlds)[l] = (unsigned)f2bf(Q0) | ((unsigned)f2bf(Q1) << 16);
    q128 = q128n;
  }

  // ---- emd = sum_{n,m<128} d * P[n] Q[m] K[n][m] + dE ; d=-log2(K)*IRSC ----
  bf16x8 qf[4];
  #pragma unroll
  for (int kt = 0; kt < 4; ++kt)
    qf[kt] = *(const bf16x8*)((const char*)Qlds + 64*kt + 16*lg);
  float accE = 0.0f;
  #pragma unroll
  for (int rt = 0; rt < 2; ++rt) {
    const float Pn = bf2f(Plds[32*wv + 16*rt + li]);
    #pragma unroll
    for (int kt = 0; kt < 4; ++kt) {
      #pragma unroll
      for (int i2 = 0; i2 < 8; ++i2) {
        const float kk = bf2f((unsigned short)KA[rt][kt][i2]);
        const float qm = bf2f((unsigned short)qf[kt][i2]);
        const float d  = -__builtin_amdgcn_logf(kk) * IRSC;
        accE = fmaf(d, (Pn * kk) * qm, accE);
      }
    }
  }
  accE = wsum64(accE);
  if (l == 0) red[wv] = accE;
  __syncthreads();
  if (t == 0) out[b] = ((red[0] + red[1]) + (red[2] + red[3])) + dE;
}

extern "C" void kernel_launch(void* const* d_in, const int* in_sizes, int n_in,
                              void* d_out, int out_size, void* d_ws, size_t ws_size,
                              hipStream_t stream) {
  const float* j1 = (const float*)d_in[0];
  const float* j2 = (const float*)d_in[1];
  float* outp = (float*)d_out;
  const int batch = in_sizes[0] / (NP * 3);
  hipLaunchKernelGGL(emd_sinkhorn, dim3(batch), dim3(256), 0, stream,
                     j1, j2, outp);
}